// Round 13
// baseline (101.312 us; speedup 1.0000x reference)
//
#include <hip/hip_runtime.h>

typedef unsigned short u16;
typedef unsigned long long u64;
typedef __attribute__((ext_vector_type(8))) short short8;   // bf16x8 MFMA fragment
typedef __attribute__((ext_vector_type(4))) float f32x4;

#define MFMA16(A,B,C) __builtin_amdgcn_mfma_f32_16x16x32_bf16(A,B,C,0,0,0)
#define NEG_INF_F (-4294967295.0f)

#define Bsz 8
#define Lsz 2048
#define Dsz 128

__device__ __forceinline__ u16 f2bf(float f){
  union { float f; unsigned u; } v; v.f = f;
  unsigned u = v.u;
  return (u16)((u + 0x7fffu + ((u >> 16) & 1u)) >> 16);
}
__device__ __forceinline__ float bf2f(u16 h){
  union { float f; unsigned u; } v; v.u = ((unsigned)h) << 16;
  return v.f;
}

// ---------------- W -> bf16 pre-conversion (once) ---------------------------
__global__ __launch_bounds__(256) void wconv_kernel(
    const float* __restrict__ Wq, const float* __restrict__ Wk,
    const float* __restrict__ Wv, u16* __restrict__ wb)
{
  int i = blockIdx.x * 256 + threadIdx.x;     // grid 192 -> 49152
  if (i < 16384) wb[i] = f2bf(Wq[i]);
  else if (i < 32768) wb[i] = f2bf(Wk[i - 16384]);
  else if (i < 49152) wb[i] = f2bf(Wv[i - 32768]);
}

// ---------------- projection: y = x @ W^T + b, Lorentz map -----------------
#define LPX 136   // bf16 pitch
#define LPY 133   // f32 pitch

__global__ __launch_bounds__(256) void proj_kernel(
    const float* __restrict__ xq, const float* __restrict__ xk, const float* __restrict__ xv,
    const u16* __restrict__ wb,
    const float* __restrict__ bq, const float* __restrict__ bk, const float* __restrict__ bv,
    const float* __restrict__ sq, const float* __restrict__ sk, const float* __restrict__ sv,
    const float* __restrict__ attn_scale,
    u16* __restrict__ qout, u16* __restrict__ kout,
    u16* __restrict__ vthi, u16* __restrict__ vtlo,
    float* __restrict__ tqo, float* __restrict__ tko,
    float* __restrict__ vpart)
{
  const int z = blockIdx.z;
  const float* x  = (z == 0) ? xq : (z == 1) ? xk : xv;
  const u16*   Wb = wb + z * 16384;
  const float* bb = (z == 0) ? bq : (z == 1) ? bk : bv;
  const float* ss = (z == 0) ? sq : (z == 1) ? sk : sv;

  __shared__ u16  xl[64 * LPX];
  __shared__ u16  wl[128 * LPX];
  __shared__ float yl[64 * LPY];
  __shared__ float scl[64];
  __shared__ float tml[64];

  const int t = threadIdx.x;
  const long row0 = (long)blockIdx.x * 64;

  for (int i = t; i < 2048; i += 256) {       // W bf16, 16B chunks
    int r = i >> 4, c8 = (i & 15) * 8;
    *(short8*)&wl[r * LPX + c8] = *(const short8*)&Wb[r * 128 + c8];
  }
  for (int i = t; i < 2048; i += 256) {       // x f32 -> bf16, 4 at a time
    int off = i * 4;
    int r = off >> 7, c = off & 127;
    f32x4 xv4 = *(const f32x4*)(x + row0 * 128 + off);
    u64 wv = (u64)f2bf(xv4[0]) | ((u64)f2bf(xv4[1]) << 16)
           | ((u64)f2bf(xv4[2]) << 32) | ((u64)f2bf(xv4[3]) << 48);
    *(u64*)&xl[r * LPX + c] = wv;
  }
  __syncthreads();

  const int l = t & 63, wid = t >> 6;
  const int qr = l & 15, g = l >> 4;
  const int r0 = wid * 16;

  short8 af[4];
#pragma unroll
  for (int ks = 0; ks < 4; ks++)
    af[ks] = *(const short8*)&xl[(r0 + qr) * LPX + ks * 32 + g * 8];

  f32x4 acc[8];
#pragma unroll
  for (int jt = 0; jt < 8; jt++) acc[jt] = (f32x4){0.f, 0.f, 0.f, 0.f};

#pragma unroll
  for (int ks = 0; ks < 4; ks++) {
#pragma unroll
    for (int jt = 0; jt < 8; jt++) {
      short8 bfr = *(const short8*)&wl[(jt * 16 + qr) * LPX + ks * 32 + g * 8];
      acc[jt] = MFMA16(af[ks], bfr, acc[jt]);
    }
  }

  float bbv[8];
#pragma unroll
  for (int jt = 0; jt < 8; jt++) bbv[jt] = bb[jt * 16 + qr];

  float ssq[4] = {0.f, 0.f, 0.f, 0.f};
#pragma unroll
  for (int jt = 0; jt < 8; jt++)
#pragma unroll
    for (int r = 0; r < 4; r++) {
      float yv = acc[jt][r] + bbv[jt];
      acc[jt][r] = yv;
      float s2 = yv * yv;
      if (jt == 0) s2 = (qr == 0) ? 0.f : s2;   // exclude d=0
      ssq[r] += s2;
    }
#pragma unroll
  for (int r = 0; r < 4; r++) {
    ssq[r] += __shfl_xor(ssq[r], 1);
    ssq[r] += __shfl_xor(ssq[r], 2);
    ssq[r] += __shfl_xor(ssq[r], 4);
    ssq[r] += __shfl_xor(ssq[r], 8);
  }

  const float es = __expf(ss[0]);
  const float fold = 2.0f / attn_scale[0];

  float tvv[4], sclv[4];
#pragma unroll
  for (int r = 0; r < 4; r++) {
    float y0 = __shfl(acc[0][r], l & 48);     // qr==0 lane of same g: d=0 value
    float tv = es / (1.0f + __expf(-y0)) + 1.1f;
    tvv[r] = tv;
    sclv[r] = sqrtf((tv * tv - 1.0f) / ssq[r]);
  }
  if (qr == 0) {
#pragma unroll
    for (int r = 0; r < 4; r++) {
      tml[r0 + g * 4 + r] = tvv[r];
      scl[r0 + g * 4 + r] = sclv[r];
    }
  }
#pragma unroll
  for (int jt = 0; jt < 8; jt++)
#pragma unroll
    for (int r = 0; r < 4; r++)
      yl[(r0 + g * 4 + r) * LPY + jt * 16 + qr] = acc[jt][r];
  __syncthreads();

  const long gbase = row0 * 128;
  if (z == 0) {
    for (int i = t; i < 64 * 128; i += 256) {
      int r = i >> 7, d = i & 127;
      float v = (d == 0) ? 0.f : yl[r * LPY + d] * scl[r] * fold;
      qout[gbase + i] = f2bf(v);
    }
    if (t < 64) tqo[row0 + t] = -tml[t] * fold;
  } else if (z == 1) {
    for (int i = t; i < 64 * 128; i += 256) {
      int r = i >> 7, d = i & 127;
      float v = (d == 0) ? 0.f : yl[r * LPY + d] * scl[r];
      kout[gbase + i] = f2bf(v);
    }
    if (t < 64) tko[row0 + t] = tml[t];
  } else {
    const int b = (int)(row0 >> 11);
    const int lpos = (int)(row0 & 2047);
    for (int i = t; i < 128 * 64; i += 256) {
      int d = i >> 6, r = i & 63;
      float v = (d == 0) ? tml[r] : yl[r * LPY + d] * scl[r];
      u16 hi = f2bf(v);
      float lo = v - bf2f(hi);
      long idx = ((long)(b * 128 + d)) * 2048 + lpos + r;
      vthi[idx] = hi;
      vtlo[idx] = f2bf(lo);
    }
    if (t < 128) {
      float s = 0.f;
      for (int r = 0; r < 64; r++)
        s += (t == 0) ? tml[r] : yl[r * LPY + t] * scl[r];
      int blk = (int)((row0 >> 6) & 31);
      vpart[((long)(b * 32 + blk)) * 128 + t] = s;
    }
  }
}

// ---------------- pack key-padding mask: one wave per 64-bit word -----------
__global__ __launch_bounds__(256) void pack_mask_kernel(
    const int* __restrict__ mask, u64* __restrict__ pmask)
{
  int gt = blockIdx.x * 256 + threadIdx.x;
  int w = gt >> 6;
  int lane = gt & 63;
  if (w >= Bsz * 32) return;
  u64 word = __ballot(mask[w * 64 + lane] != 0);
  if (lane == 0) pmask[w] = word;
}

// ---------------- deterministic v-sum reduce --------------------------------
__global__ __launch_bounds__(128) void vreduce_kernel(
    const float* __restrict__ vpart, float* __restrict__ vsum)
{
  int i = blockIdx.x * 128 + threadIdx.x;
  int b = i >> 7, d = i & 127;
  float s = 0.f;
  for (int j = 0; j < 32; j++) s += vpart[((long)(b * 32 + j)) * 128 + d];
  vsum[i] = s;
}

// ---------------- flash attention + Lorentz epilogue ------------------------
// Block = 1024 thr = ONE 32-row strip: 2 subs x 8 waves; KV-tile = 128 keys.
// Wave w QKs keys [16w,+16); PV d-sliced 16 d/wave (acc = 1 f32x4). K single-
// buffered LDS, Vhi double-buffered, P single per sub — all XOR-swizzled
// (chunk ^= row&7, pitch 128) for bank-uniform b128 access. Vlo read from L2
// (4 frags/wave, prefetched one segment early). tkv/mask prefetched 1 tile
// ahead. Pair-sequential phases (strip 63-p then p): EVERY block runs exactly
// 17 tiles. Grid 256 = 1 block/CU, 16 waves = 4/SIMD. b = blk&7 (XCD pin).
__global__ __launch_bounds__(1024, 4) void flash_kernel(
    const u16* __restrict__ qb, const u16* __restrict__ kb,
    const u16* __restrict__ vthi, const u16* __restrict__ vtlo,
    const float* __restrict__ tq, const float* __restrict__ tk,
    const u64* __restrict__ pmask, const float* __restrict__ vsum,
    float* __restrict__ out)
{
  __shared__ u16 Kl[128 * 128];         // 32 KB single, swizzled
  __shared__ u16 Vh[2][128 * 128];      // 64 KB dbuf, swizzled
  __shared__ u16 Pl[2][16 * 128];       // 8 KB per-sub single, swizzled
  __shared__ float mstat[2][8][16];
  __shared__ float lLd[2][8][16];
  __shared__ float ssqw[2][8][16];

  const int t = threadIdx.x;
  const int wv = t >> 6;
  const int sub = wv >> 3, w = wv & 7;
  const int l = t & 63;
  const int qr = l & 15, g = l >> 4;
  const int blk = blockIdx.x;
  const int b = blk & 7;                // batch == XCD (round-robin dispatch)
  const int pr = blk >> 3;              // 0..31 pair index

  // staging coords (1024 threads): row t>>3 (0..127), chunk t&7 (+8)
  const int srow = t >> 3, sch = t & 7;
  const int sphys = (sch ^ (srow & 7)) * 8;     // u16 offset of 16B chunk
  const int sbase = srow * 128 + sphys;          // +64 for chunk sch+8

  for (int phase = 0; phase < 2; ++phase) {
    const int st = phase ? pr : (63 - pr);
    const int qbase = st * 32;
    const int q0s = qbase + sub * 16;
    const int qg  = q0s + qr;
    const int nkt = (st * 32 + 159) >> 7;   // 128-key tiles covering [0,qbase+32)

    const u16* qptr = qb + ((long)(b * 2048 + qg)) * 128 + g * 8;
    short8 qf[4];
#pragma unroll
    for (int ks = 0; ks < 4; ks++) qf[ks] = *(const short8*)(qptr + ks * 32);
    const float tqv = tq[b * 2048 + qg];

    float m = NEG_INF_F, lsum = 0.f;
    f32x4 acc = (f32x4){0.f, 0.f, 0.f, 0.f};

    // ---- prologue: stage tile 0 ----
    {
      const long kgb = (long)(b * 2048 + srow) * 128;
      const long vgb = (long)(b * 128 + srow) * 2048;
      short8 a0 = *(const short8*)(kb + kgb + sch * 8);
      short8 a1 = *(const short8*)(kb + kgb + (sch + 8) * 8);
      short8 a2 = *(const short8*)(vthi + vgb + sch * 8);
      short8 a3 = *(const short8*)(vthi + vgb + (sch + 8) * 8);
      *(short8*)&Kl[sbase] = a0;
      *(short8*)&Kl[sbase + 64] = a1;
      *(short8*)&Vh[0][sbase] = a2;
      *(short8*)&Vh[0][sbase + 64] = a3;
    }
    f32x4 tkv_c = *(const f32x4*)(tk + b * 2048 + 16 * w + g * 4);
    u64 mw_c = pmask[b * 32 + (w >> 2)];
    __syncthreads();

    short8 vlo[4];                         // Vlo frags for CURRENT tile

    for (int kt = 0; kt < nkt; ++kt) {
      const int k0 = kt << 7;
      const int cur = kt & 1;
      const bool more = (kt + 1 < nkt);

      short8 s0, s1, s2, s3;
      if (more) {
        const int nk0 = k0 + 128;
        const long kgb = (long)(b * 2048 + nk0 + srow) * 128;
        const long vgb = (long)(b * 128 + srow) * 2048 + nk0;
        s0 = *(const short8*)(kb + kgb + sch * 8);
        s1 = *(const short8*)(kb + kgb + (sch + 8) * 8);
        s2 = *(const short8*)(vthi + vgb + sch * 8);
        s3 = *(const short8*)(vthi + vgb + (sch + 8) * 8);
      }

      // ---- segment A: PV(kt-1) + QK(kt) ----
      __builtin_amdgcn_s_setprio(1);
      if (kt > 0) {
        const u16* Pb = &Pl[sub][0];
        const u16* Vb = &Vh[cur ^ 1][0];
        const int vrow = (16 * w + qr) * 128;
#pragma unroll
        for (int ks2 = 0; ks2 < 4; ks2++) {
          int ch = ((g + 4 * ks2) ^ (qr & 7)) * 8;
          short8 pf = *(const short8*)&Pb[qr * 128 + ch];
          short8 vh_ = *(const short8*)&Vb[vrow + ch];
          acc = MFMA16(vh_, pf, acc);
          acc = MFMA16(vlo[ks2], pf, acc);
        }
      }
      f32x4 sv = (f32x4){0.f, 0.f, 0.f, 0.f};
      {
        const int krw = (16 * w + qr) * 128;
#pragma unroll
        for (int ks = 0; ks < 4; ks++) {
          int ch = ((g + 4 * ks) ^ (qr & 7)) * 8;
          sv = MFMA16(*(const short8*)&Kl[krw + ch], qf[ks], sv);
        }
      }
      __builtin_amdgcn_s_setprio(0);

      // issue Vlo(kt) fragment loads (consumed next segA / final PV)
      {
        const long vb = (long)(b * 128 + 16 * w + qr) * 2048 + k0 + g * 8;
#pragma unroll
        for (int ks2 = 0; ks2 < 4; ks2++)
          vlo[ks2] = *(const short8*)(vtlo + vb + ks2 * 32);
      }

      const bool bndry = (k0 + 127 > q0s);
      float p4[4];
      float tmax = NEG_INF_F;
#pragma unroll
      for (int r = 0; r < 4; r++) {
        int kl = 16 * w + g * 4 + r;
        float val = sv[r] + tqv * tkv_c[r];     // exact fp32 time product
        bool bad = ((mw_c >> (kl & 63)) & 1ull) != 0ull;
        if (bndry) bad |= (k0 + kl > qg);
        val = bad ? NEG_INF_F : val;
        p4[r] = val;
        tmax = fmaxf(tmax, val);
      }
      tmax = fmaxf(tmax, __shfl_xor(tmax, 16));
      tmax = fmaxf(tmax, __shfl_xor(tmax, 32));
      if (g == 0) mstat[sub][w][qr] = tmax;
      __syncthreads();                          // B1

      // ---- segment B: softmax finish + P write + staged LDS writes ----
      float mt = mstat[sub][0][qr];
#pragma unroll
      for (int j = 1; j < 8; j++) mt = fmaxf(mt, mstat[sub][j][qr]);
      float mn = fmaxf(m, mt);
      float rr = __expf(m - mn);
      m = mn;

      float ts = 0.f;
#pragma unroll
      for (int r = 0; r < 4; r++) {
        float pv = __expf(p4[r] - mn);
        p4[r] = pv;
        ts += pv;
      }
      {
        int pch = ((2 * w + (g >> 1)) ^ (qr & 7)) * 8 + (g & 1) * 4;
        u64 wv_ = (u64)f2bf(p4[0])
                | ((u64)f2bf(p4[1]) << 16)
                | ((u64)f2bf(p4[2]) << 32)
                | ((u64)f2bf(p4[3]) << 48);
        *(u64*)&Pl[sub][qr * 128 + pch] = wv_;
      }
      lsum = lsum * rr + ts;
      acc[0] *= rr; acc[1] *= rr; acc[2] *= rr; acc[3] *= rr;

      if (more) {
        *(short8*)&Kl[sbase] = s0;
        *(short8*)&Kl[sbase + 64] = s1;
        *(short8*)&Vh[cur ^ 1][sbase] = s2;
        *(short8*)&Vh[cur ^ 1][sbase + 64] = s3;
        tkv_c = *(const f32x4*)(tk + b * 2048 + k0 + 128 + 16 * w + g * 4);
        mw_c = pmask[b * 32 + (kt + 1) * 2 + (w >> 2)];
      }
      __syncthreads();                          // B2
    }

    // ---- final PV (last tile) ----
    {
      const u16* Pb = &Pl[sub][0];
      const u16* Vb = &Vh[(nkt - 1) & 1][0];
      const int vrow = (16 * w + qr) * 128;
#pragma unroll
      for (int ks2 = 0; ks2 < 4; ks2++) {
        int ch = ((g + 4 * ks2) ^ (qr & 7)) * 8;
        short8 pf = *(const short8*)&Pb[qr * 128 + ch];
        short8 vh_ = *(const short8*)&Vb[vrow + ch];
        acc = MFMA16(vh_, pf, acc);
        acc = MFMA16(vlo[ks2], pf, acc);
      }
    }

    // ---- epilogue (per sub): lsum merge + Lorentz normalize ----
    lsum += __shfl_xor(lsum, 16);
    lsum += __shfl_xor(lsum, 32);
    if (g == 0) lLd[sub][w][qr] = lsum;
    __syncthreads();

    float Lt = 0.f;
#pragma unroll
    for (int j = 0; j < 8; j++) Lt += lLd[sub][j][qr];
    const bool mrow = (m == NEG_INF_F);   // row fully masked -> uniform over ALL keys
    float invL = mrow ? 0.f : 1.0f / Lt;

    const float* vs = vsum + b * 128;
    float av[4];
    float pp = 0.f;
#pragma unroll
    for (int r = 0; r < 4; r++) {
      int d = 16 * w + 4 * g + r;
      float a = mrow ? vs[d] * (1.0f / 2048.0f) : acc[r] * invL;
      av[r] = a;
      pp += (d == 0) ? -a * a : a * a;
    }
    pp += __shfl_xor(pp, 16);
    pp += __shfl_xor(pp, 32);
    if (g == 0) ssqw[sub][w][qr] = pp;
    __syncthreads();

    float lor = 0.f;
#pragma unroll
    for (int j = 0; j < 8; j++) lor += ssqw[sub][j][qr];
    float rd = 1.0f / sqrtf(fmaxf(fabsf(lor), 1e-8f));

    float* op = out + ((long)(b * 2048 + qg)) * 128 + 16 * w + 4 * g;
    f32x4 o;
    o[0] = av[0] * rd; o[1] = av[1] * rd; o[2] = av[2] * rd; o[3] = av[3] * rd;
    *(f32x4*)op = o;
    __syncthreads();   // LDS safe for next phase's prologue
  }
}

// ---------------- launch ----------------------------------------------------
extern "C" void kernel_launch(void* const* d_in, const int* in_sizes, int n_in,
                              void* d_out, int out_size, void* d_ws, size_t ws_size,
                              hipStream_t stream)
{
  const float* query = (const float*)d_in[0];
  const float* key   = (const float*)d_in[1];
  const float* value = (const float*)d_in[2];
  const int*   mask  = (const int*)d_in[3];
  const float* Wq = (const float*)d_in[4];
  const float* bq = (const float*)d_in[5];
  const float* sq = (const float*)d_in[6];
  const float* Wk = (const float*)d_in[7];
  const float* bk = (const float*)d_in[8];
  const float* sk = (const float*)d_in[9];
  const float* Wv = (const float*)d_in[10];
  const float* bv = (const float*)d_in[11];
  const float* sv = (const float*)d_in[12];
  const float* attn_scale = (const float*)d_in[13];
  // d_in[14] = attn_bias: cancels in softmax, unused

  float* out = (float*)d_out;
  char* ws = (char*)d_ws;

  float* vsum  = (float*)ws;                        // 4 KB
  u64*   pmask = (u64*)(ws + 4096);                 // 2 KB (pad to 4 KB)
  float* tqa   = (float*)(ws + 8192);               // 64 KB
  float* tka   = (float*)(ws + 8192 + 65536);       // 64 KB
  float* vpart = (float*)(ws + 8192 + 131072);      // 128 KB
  u16*   wb    = (u16*)(ws + 8192 + 262144);        // 96 KB (pad to 128 KB)
  char*  big   = ws + 8192 + 262144 + 131072;
  u16*   qbuf  = (u16*)big;                         // 4 MB
  u16*   kbuf  = qbuf + (size_t)16384 * 128;        // 4 MB
  u16*   vthi  = kbuf + (size_t)16384 * 128;        // 4 MB
  u16*   vtlo  = vthi + (size_t)16384 * 128;        // 4 MB

  wconv_kernel<<<192, 256, 0, stream>>>(Wq, Wk, Wv, wb);
  proj_kernel<<<dim3(256, 1, 3), 256, 0, stream>>>(
      query, key, value, wb, bq, bk, bv, sq, sk, sv, attn_scale,
      qbuf, kbuf, vthi, vtlo, tqa, tka, vpart);
  pack_mask_kernel<<<64, 256, 0, stream>>>(mask, pmask);
  vreduce_kernel<<<8, 128, 0, stream>>>(vpart, vsum);
  flash_kernel<<<256, 1024, 0, stream>>>(
      qbuf, kbuf, vthi, vtlo, tqa, tka, pmask, vsum, out);
}